// Round 1
// baseline (880.668 us; speedup 1.0000x reference)
//
#include <hip/hip_runtime.h>
#include <hip/hip_bf16.h>

// GNN edge-conv: fused bf16-MFMA pipeline.
// ws layout (bytes):
//   agg   f32 [50000][256]  @ 0          (51,200,000)
//   cnt   f32 [50000]       @ 51,200,000 (200,000)
//   xb    bf16[50000][128]  @ 51,400,192 (12,800,000)
//   hb    bf16[50000][128]  @ 64,200,192 (12,800,000)
//   w1f   bf16 frag         @ 77,000,192 (131,072)
//   w3f   bf16 frag         @ 77,131,264 (65,536)
//   w4f   bf16 frag(pad48)  @ 77,196,800 (12,288)
//   b4p   f32 [48]          @ 77,209,088 (192)
//   flag  int (edge idx is int64?) @ 77,209,280
// total ~77.3 MB

typedef short bf16x8 __attribute__((ext_vector_type(8)));
typedef float f32x4 __attribute__((ext_vector_type(4)));

#define N_NODES 50000
#define N_EDGES 800000

__device__ __forceinline__ unsigned short f2bf(float f) {
  unsigned u = __builtin_bit_cast(unsigned, f);
  u = u + 0x7fffu + ((u >> 16) & 1u);      // RNE
  return (unsigned short)(u >> 16);
}

// edge_index may be stored as int32 or int64 (harness doc says int32; probe decides).
__device__ __forceinline__ int ld_src(const int* ei, int m64, int e) {
  return m64 ? ei[2 * e] : ei[e];
}
__device__ __forceinline__ int ld_dst(const int* ei, int m64, int e) {
  return m64 ? ei[2 * N_EDGES + 2 * e] : ei[N_EDGES + e];
}

__global__ void k_prep_xb(const float* __restrict__ x, unsigned short* __restrict__ xb) {
  long i = ((long)blockIdx.x * 256 + threadIdx.x) * 4;
  float4 v = *(const float4*)(x + i);
  ushort4 o;
  o.x = f2bf(v.x); o.y = f2bf(v.y); o.z = f2bf(v.z); o.w = f2bf(v.w);
  *(ushort4*)(xb + i) = o;
}

// Pack W into MFMA B-fragment order: [ct][ks][lane][i], value = W[ks*32+(lane>>4)*8+i][ct*16+(lane&15)]
__device__ __forceinline__ void fill8(unsigned short* dst, const float* W, int f, int C) {
  int i = f & 7, lane = (f >> 3) & 63, ks = (f >> 9) & 7, ct = f >> 12;
  int k = ks * 32 + (lane >> 4) * 8 + i;
  int c = ct * 16 + (lane & 15);
  dst[f] = f2bf(W[k * C + c]);
}

__global__ void k_prep_frags(const float* __restrict__ W1, const float* __restrict__ W3,
                             const float* __restrict__ W4, const float* __restrict__ b4,
                             unsigned short* __restrict__ w1f, unsigned short* __restrict__ w3f,
                             unsigned short* __restrict__ w4f, float* __restrict__ b4p,
                             int* __restrict__ flagp, const int* __restrict__ ei) {
  int gid = blockIdx.x * 256 + threadIdx.x;
  if (gid < 65536) {
    fill8(w1f, W1, gid, 256);                       // W1 [256][256], CT=16 KS=8
  } else if (gid < 98304) {
    fill8(w3f, W3, gid - 65536, 128);               // W3 [256][128], CT=8 KS=8
  } else if (gid < 104448) {                        // W4 [128][40] pad to 48 cols, CT=3 KS=4
    int f = gid - 98304;
    int i = f & 7, lane = (f >> 3) & 63, ks = (f >> 9) & 3, ct = f >> 11;
    int k = ks * 32 + (lane >> 4) * 8 + i;
    int c = ct * 16 + (lane & 15);
    w4f[f] = (c < 40) ? f2bf(W4[k * 40 + c]) : (unsigned short)0;
  } else if (gid < 104496) {
    int c = gid - 104448;
    b4p[c] = (c < 40) ? b4[c] : 0.f;
  } else if (gid == 104496) {
    // int64 edge_index => high words of first few values are all zero
    *flagp = (ei[1] == 0 && ei[3] == 0 && ei[5] == 0 && ei[7] == 0) ? 1 : 0;
  }
}

// K1: eh = relu([x_src,x_dst]@W1+b1); atomic scatter into agg[dst]; also count.
// 128 edges/block, 4 waves; wave owns 4 of 16 col-tiles, W1-frags held in registers.
__global__ __launch_bounds__(256, 2) void k_edge_mlp1(
    const unsigned short* __restrict__ xb, const int* __restrict__ ei,
    const unsigned short* __restrict__ w1f, const float* __restrict__ b1,
    float* __restrict__ agg, float* __restrict__ cnt, const int* __restrict__ flagp) {
  __shared__ __attribute__((aligned(16))) short Et[128 * 256];  // 64 KB, XOR-swizzled
  const int t = threadIdx.x;
  const int m64 = *flagp;
  const int eb = blockIdx.x * 128;

  if (t < 128) {
    int d = ld_dst(ei, m64, eb + t);
    __hip_atomic_fetch_add(&cnt[d], 1.0f, __ATOMIC_RELAXED, __HIP_MEMORY_SCOPE_AGENT);
  }

  const int w = t >> 6, l = t & 63, lr = l & 15, lh = l >> 4;

  bf16x8 B[4][8];
#pragma unroll
  for (int ci = 0; ci < 4; ++ci)
#pragma unroll
    for (int ks = 0; ks < 8; ++ks)
      B[ci][ks] = *(const bf16x8*)(w1f + (((4 * w + ci) * 8 + ks) * 64 + l) * 8);
  float b1c[4];
#pragma unroll
  for (int ci = 0; ci < 4; ++ci) b1c[ci] = b1[(4 * w + ci) * 16 + lr];

  // stage concat(x[src],x[dst]) as bf16: 128 rows x 256 cols
#pragma unroll
  for (int j = 0; j < 16; ++j) {
    int c = t + 256 * j;
    int row = c >> 5, q = c & 31, endp = q >> 4, ck = q & 15;
    int e = eb + row;
    int node = endp ? ld_dst(ei, m64, e) : ld_src(ei, m64, e);
    int4 v = *(const int4*)(xb + ((long)node << 7) + (ck << 3));
    int off = (row << 9) + (endp << 8) + (ck << 4);
    off ^= (row & 7) << 4;
    *(int4*)((char*)Et + off) = v;
  }
  __syncthreads();

#pragma unroll 1
  for (int rt = 0; rt < 8; ++rt) {
    f32x4 acc[4] = {};
#pragma unroll
    for (int ks = 0; ks < 8; ++ks) {
      int row = (rt << 4) + lr;
      int off = (row << 9) + (ks << 6) + (lh << 4);
      off ^= (row & 7) << 4;
      bf16x8 a = *(const bf16x8*)((const char*)Et + off);
#pragma unroll
      for (int ci = 0; ci < 4; ++ci)
        acc[ci] = __builtin_amdgcn_mfma_f32_16x16x32_bf16(a, B[ci][ks], acc[ci], 0, 0, 0);
    }
    int dsts[4];
#pragma unroll
    for (int r = 0; r < 4; ++r) dsts[r] = ld_dst(ei, m64, eb + (rt << 4) + (lh << 2) + r);
#pragma unroll
    for (int ci = 0; ci < 4; ++ci) {
      int col = (4 * w + ci) * 16 + lr;
#pragma unroll
      for (int r = 0; r < 4; ++r) {
        float v = fmaxf(acc[ci][r] + b1c[ci], 0.f);
        __hip_atomic_fetch_add(&agg[dsts[r] * 256 + col], v, __ATOMIC_RELAXED,
                               __HIP_MEMORY_SCOPE_AGENT);
      }
    }
  }
}

// K2: mean = agg/max(cnt,1); h = relu(mean@W2+b2) -> hb (bf16). f32 VALU (3.3 GFLOP).
__global__ __launch_bounds__(256) void k_node_mlp(
    const float* __restrict__ agg, const float* __restrict__ cnt,
    const float* __restrict__ W2, const float* __restrict__ b2,
    unsigned short* __restrict__ hb) {
  __shared__ __attribute__((aligned(16))) float mean[16][256];
  __shared__ float inv_s[16];
  const int t = threadIdx.x;
  const int nb = blockIdx.x * 16;
  if (t < 16) inv_s[t] = 1.0f / fmaxf(cnt[nb + t], 1.0f);
  __syncthreads();
#pragma unroll
  for (int m = 0; m < 16; ++m) {
    int idx = t + 256 * m;
    int nn = idx >> 8, k = idx & 255;
    mean[nn][k] = agg[(long)(nb + nn) * 256 + k] * inv_s[nn];
  }
  __syncthreads();
  const int c = t & 127, h = t >> 7;
  float sum[8];
#pragma unroll
  for (int j = 0; j < 8; ++j) sum[j] = b2[c];
  for (int k4 = 0; k4 < 256; k4 += 4) {
    float wv[4];
#pragma unroll
    for (int kk = 0; kk < 4; ++kk) wv[kk] = W2[(k4 + kk) * 128 + c];
#pragma unroll
    for (int j = 0; j < 8; ++j) {
      float4 m = *(const float4*)&mean[h * 8 + j][k4];
      sum[j] = fmaf(m.x, wv[0], fmaf(m.y, wv[1], fmaf(m.z, wv[2], fmaf(m.w, wv[3], sum[j]))));
    }
  }
#pragma unroll
  for (int j = 0; j < 8; ++j)
    hb[(long)(nb + h * 8 + j) * 128 + c] = f2bf(fmaxf(sum[j], 0.f));
}

// K3: z = relu([h_src,h_dst]@W3+b3); logits = z@W4+b4; log_softmax -> out.
// 64 edges/block, 4 waves.
__global__ __launch_bounds__(256, 2) void k_edge_head(
    const unsigned short* __restrict__ hb, const int* __restrict__ ei,
    const unsigned short* __restrict__ w3f, const float* __restrict__ b3,
    const unsigned short* __restrict__ w4f, const float* __restrict__ b4p,
    float* __restrict__ out, const int* __restrict__ flagp) {
  __shared__ __attribute__((aligned(16))) char L[49152];
  short* e2 = (short*)L;            // 32 KB  (stage input)
  short* zb = (short*)(L + 32768);  // 16 KB  (z bf16)
  float* lg = (float*)L;            // 12 KB  (logits, aliases e2 after stage1)
  const int t = threadIdx.x;
  const int m64 = *flagp;
  const int eb = blockIdx.x * 64;
  const int w = t >> 6, l = t & 63, lr = l & 15, lh = l >> 4;

  bf16x8 B3[2][8];
#pragma unroll
  for (int ci = 0; ci < 2; ++ci)
#pragma unroll
    for (int ks = 0; ks < 8; ++ks)
      B3[ci][ks] = *(const bf16x8*)(w3f + (((2 * w + ci) * 8 + ks) * 64 + l) * 8);
  float b3c[2];
#pragma unroll
  for (int ci = 0; ci < 2; ++ci) b3c[ci] = b3[(2 * w + ci) * 16 + lr];

#pragma unroll
  for (int j = 0; j < 8; ++j) {
    int c = t + 256 * j;
    int row = c >> 5, q = c & 31, endp = q >> 4, ck = q & 15;
    int e = eb + row;
    int node = endp ? ld_dst(ei, m64, e) : ld_src(ei, m64, e);
    int4 v = *(const int4*)(hb + ((long)node << 7) + (ck << 3));
    int off = (row << 9) + (endp << 8) + (ck << 4);
    off ^= (row & 7) << 4;
    *(int4*)((char*)e2 + off) = v;
  }
  __syncthreads();

  // stage 1: z tiles -> zb (bf16, swizzled). Wave owns 2 of 8 col-tiles.
#pragma unroll 1
  for (int rt = 0; rt < 4; ++rt) {
    f32x4 acc[2] = {};
#pragma unroll
    for (int ks = 0; ks < 8; ++ks) {
      int row = (rt << 4) + lr;
      int off = (row << 9) + (ks << 6) + (lh << 4);
      off ^= (row & 7) << 4;
      bf16x8 a = *(const bf16x8*)((const char*)e2 + off);
#pragma unroll
      for (int ci = 0; ci < 2; ++ci)
        acc[ci] = __builtin_amdgcn_mfma_f32_16x16x32_bf16(a, B3[ci][ks], acc[ci], 0, 0, 0);
    }
#pragma unroll
    for (int ci = 0; ci < 2; ++ci) {
      int col = (2 * w + ci) * 16 + lr;
#pragma unroll
      for (int r = 0; r < 4; ++r) {
        int row = (rt << 4) + (lh << 2) + r;
        float v = fmaxf(acc[ci][r] + b3c[ci], 0.f);
        int off = (row << 8) + (col << 1);
        off ^= (row & 7) << 4;
        *(short*)((char*)zb + off) = (short)f2bf(v);
      }
    }
  }
  __syncthreads();

  // stage 2: logits = zb @ W4 (48 padded cols). Wave owns row-strip w, all 3 col-tiles.
  bf16x8 B4[3][4];
#pragma unroll
  for (int ci = 0; ci < 3; ++ci)
#pragma unroll
    for (int ks = 0; ks < 4; ++ks)
      B4[ci][ks] = *(const bf16x8*)(w4f + ((ci * 4 + ks) * 64 + l) * 8);
  f32x4 acc2[3] = {};
#pragma unroll
  for (int ks = 0; ks < 4; ++ks) {
    int row = (w << 4) + lr;
    int off = (row << 8) + (ks << 6) + (lh << 4);
    off ^= (row & 7) << 4;
    bf16x8 a = *(const bf16x8*)((const char*)zb + off);
#pragma unroll
    for (int ci = 0; ci < 3; ++ci)
      acc2[ci] = __builtin_amdgcn_mfma_f32_16x16x32_bf16(a, B4[ci][ks], acc2[ci], 0, 0, 0);
  }
#pragma unroll
  for (int ci = 0; ci < 3; ++ci) {
    int col = ci * 16 + lr;
    float bb = b4p[col];
#pragma unroll
    for (int r = 0; r < 4; ++r) {
      int row = (w << 4) + (lh << 2) + r;
      lg[row * 48 + col] = acc2[ci][r] + bb;
    }
  }
  __syncthreads();

  // log-softmax over 40 classes; 4 threads per row (same wave), shfl_xor reduce.
  const int r = t >> 2, q = t & 3;
  float v[10], mx = -1e30f;
#pragma unroll
  for (int j = 0; j < 10; ++j) {
    v[j] = lg[r * 48 + q + 4 * j];
    mx = fmaxf(mx, v[j]);
  }
  mx = fmaxf(mx, __shfl_xor(mx, 1, 64));
  mx = fmaxf(mx, __shfl_xor(mx, 2, 64));
  float s = 0.f;
#pragma unroll
  for (int j = 0; j < 10; ++j) s += __expf(v[j] - mx);
  s += __shfl_xor(s, 1, 64);
  s += __shfl_xor(s, 2, 64);
  float lse = mx + __logf(s);
#pragma unroll
  for (int j = 0; j < 10; ++j) out[(long)(eb + r) * 40 + q + 4 * j] = v[j] - lse;
}

extern "C" void kernel_launch(void* const* d_in, const int* in_sizes, int n_in,
                              void* d_out, int out_size, void* d_ws, size_t ws_size,
                              hipStream_t stream) {
  const float* x = (const float*)d_in[0];
  const int* ei = (const int*)d_in[1];
  const float* W1 = (const float*)d_in[2];
  const float* b1 = (const float*)d_in[3];
  const float* W2 = (const float*)d_in[4];
  const float* b2 = (const float*)d_in[5];
  const float* W3 = (const float*)d_in[6];
  const float* b3 = (const float*)d_in[7];
  const float* W4 = (const float*)d_in[8];
  const float* b4 = (const float*)d_in[9];
  char* ws = (char*)d_ws;
  float* agg = (float*)(ws + 0);
  float* cnt = (float*)(ws + 51200000);
  unsigned short* xb = (unsigned short*)(ws + 51400192);
  unsigned short* hb = (unsigned short*)(ws + 64200192);
  unsigned short* w1f = (unsigned short*)(ws + 77000192);
  unsigned short* w3f = (unsigned short*)(ws + 77131264);
  unsigned short* w4f = (unsigned short*)(ws + 77196800);
  float* b4p = (float*)(ws + 77209088);
  int* flagp = (int*)(ws + 77209280);
  float* out = (float*)d_out;

  hipMemsetAsync(ws, 0, 51400000, stream);  // agg + cnt
  k_prep_xb<<<6250, 256, 0, stream>>>(x, xb);
  k_prep_frags<<<409, 256, 0, stream>>>(W1, W3, W4, b4, w1f, w3f, w4f, b4p, flagp, ei);
  k_edge_mlp1<<<6250, 256, 0, stream>>>(xb, ei, w1f, b1, agg, cnt, flagp);
  k_node_mlp<<<3125, 256, 0, stream>>>(agg, cnt, W2, b2, hb);
  k_edge_head<<<12500, 256, 0, stream>>>(hb, ei, w3f, b3, w4f, b4p, out, flagp);
}